// Round 7
// baseline (276.148 us; speedup 1.0000x reference)
//
#include <hip/hip_runtime.h>
#include <hip/hip_bf16.h>
#include <stdint.h>

#define EMBED 2048
#define NHEADS 32
#define HDIM 64
#define BATCH 2
#define SEQ 2048
#define ATT_SCALE 0.125f
#define LOG2E 1.4426950408889634f

typedef __attribute__((ext_vector_type(8))) short bf16x8;
typedef __attribute__((ext_vector_type(4))) float f32x4;
typedef __attribute__((ext_vector_type(16))) float f32x16;
typedef __attribute__((ext_vector_type(4))) unsigned short u16x4;
typedef __attribute__((ext_vector_type(2))) unsigned int u32x2;

static __device__ __forceinline__ unsigned short f2bf(float f) {
  union { float f; uint32_t u; } v; v.f = f;
  uint32_t r = v.u + 0x7fffu + ((v.u >> 16) & 1u);
  return (unsigned short)(r >> 16);
}

static __device__ __forceinline__ void gload_lds16(const unsigned short* g, unsigned short* l) {
  __builtin_amdgcn_global_load_lds(
      (const __attribute__((address_space(1))) unsigned int*)g,
      (__attribute__((address_space(3))) unsigned int*)l, 16, 0, 0);
}

// ---------------- fp32 -> bf16 cast, all 5 tensors fused ----------------
__global__ void cvt_all(const float* __restrict__ h,
                        const float* __restrict__ Wq, const float* __restrict__ Wk,
                        const float* __restrict__ Wv, const float* __restrict__ Wo,
                        unsigned short* __restrict__ out) {
  const int n4 = 6291456;
  int idx = blockIdx.x * blockDim.x + threadIdx.x;
  int stride = gridDim.x * blockDim.x;
  for (int i = idx; i < n4; i += stride) {
    const float* src; int off;
    if (i < 2097152)      { src = h;  off = i; }
    else if (i < 3145728) { src = Wq; off = i - 2097152; }
    else if (i < 4194304) { src = Wk; off = i - 3145728; }
    else if (i < 5242880) { src = Wv; off = i - 4194304; }
    else                  { src = Wo; off = i - 5242880; }
    float4 v = ((const float4*)src)[off];
    u16x4 o;
    o.x = f2bf(v.x); o.y = f2bf(v.y); o.z = f2bf(v.z); o.w = f2bf(v.w);
    ((u16x4*)out)[i] = o;
  }
}

// ---------------- 256x256 8-phase GEMM (m201 geometry) for QKV ----------------
// C[4096,6144] = A[4096,2048] @ W[6144,2048]^T, fused QKV epilogue.
// BM=BN=256, BK=64; 512 threads = 8 waves (2M x 4N), wave tile 128x64.
// 4 phases/K-tile, 16 MFMA each; counted vmcnt(4)/vmcnt(2), never 0 steady-state.
// LDS swizzle: LDS[r][u] = G[r][u ^ (r&7)] (16B units), both sides.
__global__ __launch_bounds__(512, 2)
void gemm256_qkv(const unsigned short* __restrict__ A,
                 const unsigned short* __restrict__ W,
                 const float* __restrict__ b0, const float* __restrict__ b1,
                 const float* __restrict__ b2,
                 unsigned short* __restrict__ o0, unsigned short* __restrict__ o1,
                 unsigned short* __restrict__ o2, float qscale) {
  __shared__ unsigned short lds[2][32768];  // per buf: A [256][64] @0, B [256][64] @16384
  const int tid = threadIdx.x;
  const int w = tid >> 6, l = tid & 63;
  const int wm = w >> 2, wn = w & 3;
  const int r16 = l & 15, g = l >> 4;
  // XCD 2x4 chunk map: xcd (xr,xc) owns bi in [xr*8,xr*8+8), bj in [xc*6,xc*6+6)
  const int xcd = blockIdx.x & 7, t8 = blockIdx.x >> 3;   // t8 in [0,48)
  const int bi = (xcd >> 2) * 8 + (t8 & 7);
  const int bj = (xcd & 3) * 6 + (t8 >> 3);
  const int arow0 = bi * 256, bcol0 = bj * 256;

  f32x4 acc[8][4];
#pragma unroll
  for (int i = 0; i < 8; ++i)
#pragma unroll
    for (int j = 0; j < 4; ++j) acc[i][j] = (f32x4){0.f, 0.f, 0.f, 0.f};

  const int lr8 = (l >> 3) & 7;
  const int gcu = ((l & 7) ^ lr8) * 8;          // pre-swizzled source col (elements)
  const int wb = (w & 3) * 8 + (w >> 2) * 64;   // B strip base per wave

  // A call: 64 rows starting at `base` (base in {0,64,128,192})
  auto stageA = [&](int buf, int kt, int base) {
    gload_lds16(A + (size_t)(arow0 + base + (tid >> 3)) * 2048 + kt * 64 + gcu,
                &lds[buf][(base + w * 8) * 64]);
  };
  // B call: strips for nh half; k in {0,1}: rows {wb + nh*32 + k*128 + (l>>3)}
  auto stageB = [&](int buf, int kt, int nh, int k) {
    const int rbase = wb + nh * 32 + k * 128;
    gload_lds16(W + (size_t)(bcol0 + rbase + (l >> 3)) * 2048 + kt * 64 + gcu,
                &lds[buf][16384 + rbase * 64]);
  };
  auto ldA = [&](int buf, int mf, int ks) -> bf16x8 {
    const int row = wm * 128 + mf * 16 + r16;
    const int u = (ks * 4 + g) ^ (r16 & 7);
    return *(const bf16x8*)&lds[buf][row * 64 + u * 8];
  };
  auto ldB = [&](int buf, int nf, int ks) -> bf16x8 {
    const int row = wn * 64 + nf * 16 + r16;
    const int u = (ks * 4 + g) ^ (r16 & 7);
    return *(const bf16x8*)&lds[buf][16384 + row * 64 + u * 8];
  };

  bf16x8 af[4][2], bfr[4][2];

#define MMA_Q(MH, NH)                                                              \
  __builtin_amdgcn_s_setprio(1);                                                   \
  _Pragma("unroll")                                                                \
  for (int i = 0; i < 4; ++i)                                                      \
    _Pragma("unroll")                                                              \
    for (int j = 0; j < 2; ++j)                                                    \
      _Pragma("unroll")                                                            \
      for (int ks = 0; ks < 2; ++ks)                                               \
        acc[(MH)*4 + i][(NH)*2 + j] = __builtin_amdgcn_mfma_f32_16x16x32_bf16(     \
            af[i][ks], bfr[(NH)*2 + j][ks], acc[(MH)*4 + i][(NH)*2 + j], 0, 0, 0); \
  __builtin_amdgcn_s_setprio(0);

  // prologue: tile 0 -> buf0; A-late (64,192) issued LAST (may stay in flight)
  stageB(0, 0, 0, 0); stageB(0, 0, 0, 1);
  stageB(0, 0, 1, 0); stageB(0, 0, 1, 1);
  stageA(0, 0, 0); stageA(0, 0, 128);
  stageA(0, 0, 64); stageA(0, 0, 192);
  asm volatile("s_waitcnt vmcnt(2)" ::: "memory");
  __builtin_amdgcn_sched_barrier(0);
  __builtin_amdgcn_s_barrier();

  const int nt = 32;  // K = 2048 / 64
  for (int c = 0; c < nt; ++c) {
    const int X = c & 1, Y = X ^ 1;
    const bool s1 = (c + 1 < nt);
    // ---- Phase 0: quad (mh0, nh0); stage B_h0(c+1)
#pragma unroll
    for (int i = 0; i < 4; ++i) { af[i][0] = ldA(X, i, 0); af[i][1] = ldA(X, i, 1); }
#pragma unroll
    for (int j = 0; j < 2; ++j) { bfr[j][0] = ldB(X, j, 0); bfr[j][1] = ldB(X, j, 1); }
    if (s1) { stageB(Y, c + 1, 0, 0); stageB(Y, c + 1, 0, 1); }
    MMA_Q(0, 0);
    __builtin_amdgcn_s_barrier();
    // ---- Phase 1: quad (mh0, nh1); stage B_h1(c+1)
#pragma unroll
    for (int j = 2; j < 4; ++j) { bfr[j][0] = ldB(X, j, 0); bfr[j][1] = ldB(X, j, 1); }
    if (s1) { stageB(Y, c + 1, 1, 0); stageB(Y, c + 1, 1, 1); }
    MMA_Q(0, 1);
    __builtin_amdgcn_s_barrier();
    // ---- Phase 2: quad (mh1, nh0); needs A-late(c): gate vmcnt; stage A-early(c+1)
    if (s1) asm volatile("s_waitcnt vmcnt(4)" ::: "memory");
    else    asm volatile("s_waitcnt vmcnt(0)" ::: "memory");
    __builtin_amdgcn_sched_barrier(0);
#pragma unroll
    for (int i = 0; i < 4; ++i) { af[i][0] = ldA(X, i + 4, 0); af[i][1] = ldA(X, i + 4, 1); }
    if (s1) { stageA(Y, c + 1, 0); stageA(Y, c + 1, 128); }
    MMA_Q(1, 0);
    __builtin_amdgcn_s_barrier();
    // ---- Phase 3: quad (mh1, nh1); stage A-late(c+1); end gate vmcnt(2)
    if (s1) { stageA(Y, c + 1, 64); stageA(Y, c + 1, 192); }
    MMA_Q(1, 1);
    if (s1) asm volatile("s_waitcnt vmcnt(2)" ::: "memory");
    else    asm volatile("s_waitcnt vmcnt(0)" ::: "memory");
    __builtin_amdgcn_sched_barrier(0);
    __builtin_amdgcn_s_barrier();
  }
#undef MMA_Q

  // epilogue: bias + scale + QKV scatter
  const int which = bj >> 3;  // 0=Q 1=K 2=V (block-uniform)
  const float* bb = (which == 0) ? b0 : (which == 1) ? b1 : b2;
  const float osc = (which == 0) ? qscale : 1.0f;
  unsigned short* outp = (which == 0) ? o0 : (which == 1) ? o1 : o2;
#pragma unroll
  for (int mf = 0; mf < 8; ++mf) {
    const int irow = arow0 + wm * 128 + mf * 16 + g * 4;
#pragma unroll
    for (int nf = 0; nf < 4; ++nf) {
      const int jcol = bcol0 + wn * 64 + nf * 16 + r16;
      const int jl = jcol & 2047;
      const int hh = jl >> 6, d = jl & 63;
      const float bval = bb[jl];
#pragma unroll
      for (int rr = 0; rr < 4; ++rr) {
        const float val = (acc[mf][nf][rr] + bval) * osc;
        const int i = irow + rr;
        const int b = i >> 11, s = i & 2047;
        size_t off;
        if (which < 2) off = (((size_t)(b * NHEADS + hh)) * SEQ + s) * HDIM + d;
        else           off = (((size_t)(b * NHEADS + hh)) * HDIM + d) * SEQ + s;
        outp[off] = f2bf(val);
      }
    }
  }
}

// ---------------- 256x128 pipelined GEMM (out-proj): fp32 out + bias ----------------
__global__ __launch_bounds__(512, 2)
void gemm8_out(const unsigned short* __restrict__ A,
               const unsigned short* __restrict__ W,
               const float* __restrict__ bias, float* __restrict__ fo) {
  __shared__ unsigned short lds[2][24576];   // per buf: A [256][64] @0, B [128][64] @16384
  const int tid = threadIdx.x;
  const int w = tid >> 6, l = tid & 63;
  const int wm = w >> 1, wn = w & 1;
  const int r16 = l & 15, g = l >> 4;
  const int NBJ = 16, nblk = 256;
  const int swz = (blockIdx.x & 7) * (nblk >> 3) + (blockIdx.x >> 3);
  const int bi = swz / NBJ, bj = swz % NBJ;
  const int arow0 = bi * 256, bcol0 = bj * 128;

  f32x4 acc[4][4];
#pragma unroll
  for (int i = 0; i < 4; ++i)
#pragma unroll
    for (int j = 0; j < 4; ++j) acc[i][j] = (f32x4){0.f, 0.f, 0.f, 0.f};

  const int lrow = l >> 3;
  const int gcu = ((l & 7) ^ lrow) * 8;

  auto stageA = [&](int buf, int t, int mq, int call) {
    const int m = call * 8 + w;
    const int row0 = mq * 32 + (m >> 2) * 64 + (m & 3) * 8;
    gload_lds16(A + (size_t)(arow0 + row0 + lrow) * 2048 + t * 64 + gcu,
                &lds[buf][row0 * 64]);
  };
  auto stageB = [&](int buf, int t, int nq) {
    const int row0 = nq * 32 + (w >> 2) * 64 + (w & 3) * 8;
    gload_lds16(W + (size_t)(bcol0 + row0 + lrow) * 2048 + t * 64 + gcu,
                &lds[buf][16384 + row0 * 64]);
  };
  auto ldA = [&](int buf, int mf, int ks) -> bf16x8 {
    const int row = wm * 64 + mf * 16 + r16;
    const int u = (ks * 4 + g) ^ (r16 & 7);
    return *(const bf16x8*)&lds[buf][row * 64 + u * 8];
  };
  auto ldB = [&](int buf, int nf, int ks) -> bf16x8 {
    const int row = wn * 64 + nf * 16 + r16;
    const int u = (ks * 4 + g) ^ (r16 & 7);
    return *(const bf16x8*)&lds[buf][16384 + row * 64 + u * 8];
  };

  stageA(0, 0, 0, 0); stageA(0, 0, 0, 1); stageB(0, 0, 0);
  stageA(0, 0, 1, 0); stageA(0, 0, 1, 1); stageB(0, 0, 1);
  stageA(1, 1, 0, 0); stageA(1, 1, 0, 1); stageB(1, 1, 0);
  asm volatile("s_waitcnt vmcnt(3)" ::: "memory");
  __builtin_amdgcn_sched_barrier(0);
  __builtin_amdgcn_s_barrier();

  bf16x8 af[2][2], bfr[4][2];

#define MMA_Q(MQ, NQ)                                                          \
  __builtin_amdgcn_s_setprio(1);                                               \
  _Pragma("unroll")                                                            \
  for (int i = 0; i < 2; ++i)                                                  \
    _Pragma("unroll")                                                          \
    for (int j = 0; j < 2; ++j)                                                \
      _Pragma("unroll")                                                        \
      for (int ks = 0; ks < 2; ++ks)                                           \
        acc[(MQ)*2 + i][(NQ)*2 + j] = __builtin_amdgcn_mfma_f32_16x16x32_bf16( \
            af[i][ks], bfr[(NQ)*2 + j][ks], acc[(MQ)*2 + i][(NQ)*2 + j], 0, 0, 0); \
  __builtin_amdgcn_s_setprio(0);

  const int nt = 32;
  for (int c = 0; c < nt; ++c) {
    const int X = c & 1;
    const bool s1 = (c + 1 < nt), s2 = (c + 2 < nt);
    af[0][0] = ldA(X, 0, 0); af[0][1] = ldA(X, 0, 1);
    af[1][0] = ldA(X, 1, 0); af[1][1] = ldA(X, 1, 1);
    bfr[0][0] = ldB(X, 0, 0); bfr[0][1] = ldB(X, 0, 1);
    bfr[1][0] = ldB(X, 1, 0); bfr[1][1] = ldB(X, 1, 1);
    if (s1) { stageA(X ^ 1, c + 1, 1, 0); stageA(X ^ 1, c + 1, 1, 1); }
    MMA_Q(0, 0);
    __builtin_amdgcn_s_barrier();
    bfr[2][0] = ldB(X, 2, 0); bfr[2][1] = ldB(X, 2, 1);
    bfr[3][0] = ldB(X, 3, 0); bfr[3][1] = ldB(X, 3, 1);
    if (s1) stageB(X ^ 1, c + 1, 1);
    MMA_Q(0, 1);
    __builtin_amdgcn_s_barrier();
    af[0][0] = ldA(X, 2, 0); af[0][1] = ldA(X, 2, 1);
    af[1][0] = ldA(X, 3, 0); af[1][1] = ldA(X, 3, 1);
    if (s2) { stageA(X, c + 2, 0, 0); stageA(X, c + 2, 0, 1); }
    MMA_Q(1, 0);
    __builtin_amdgcn_s_barrier();
    if (s2) stageB(X, c + 2, 0);
    MMA_Q(1, 1);
    if (s2) asm volatile("s_waitcnt vmcnt(3)" ::: "memory");
    else    asm volatile("s_waitcnt vmcnt(0)" ::: "memory");
    __builtin_amdgcn_sched_barrier(0);
    __builtin_amdgcn_s_barrier();
  }
#undef MMA_Q

#pragma unroll
  for (int mf = 0; mf < 4; ++mf) {
    const int irow = arow0 + wm * 64 + mf * 16 + g * 4;
#pragma unroll
    for (int nf = 0; nf < 4; ++nf) {
      const int jcol = bcol0 + wn * 64 + nf * 16 + r16;
      const float bval = bias[jcol];
#pragma unroll
      for (int rr = 0; rr < 4; ++rr)
        fo[(size_t)(irow + rr) * 2048 + jcol] = acc[mf][nf][rr] + bval;
    }
  }
}

// ---------------- causal flash attention, swapped 32x32 QK^T, in-register softmax ----------------
__global__ __launch_bounds__(256, 2)
void attn_kernel(const unsigned short* __restrict__ Q,
                 const unsigned short* __restrict__ K,
                 const unsigned short* __restrict__ Vt,
                 unsigned short* __restrict__ O) {
  __shared__ unsigned short K_lds[2][64 * 72];
  __shared__ unsigned short V_lds[2][64 * 72];
  __shared__ __align__(16) float abuf[4][32];
  __shared__ __align__(16) float lbuf[4][32];
  const int tid = threadIdx.x;
  const int w = tid >> 6, l = tid & 63;
  const int q5 = l & 31, hi = l >> 5;
  const int bid = ((blockIdx.x & 7) << 6) | (blockIdx.x >> 3);
  const int pair = bid & 7;
  const int bh = bid >> 3;
  const unsigned short* Qh = Q + (size_t)bh * SEQ * HDIM;
  const unsigned short* Kh = K + (size_t)bh * SEQ * HDIM;
  const unsigned short* Vh = Vt + (size_t)bh * HDIM * SEQ;
  const int bq = bh >> 5, hh = bh & 31;
  const int srow = tid >> 3;
  const int scol = (tid & 7) * 8;

  for (int half = 0; half < 2; ++half) {
    const int qt = half ? (15 - pair) : pair;
    const int wrow0 = qt * 128 + w * 32;
    const int wrow_max = wrow0 + 31;
    const int n_tiles = 2 * qt + 2;
    const int qrow = wrow0 + q5;

    bf16x8 qf[4];
#pragma unroll
    for (int ks = 0; ks < 4; ++ks)
      qf[ks] = *(const bf16x8*)(Qh + (size_t)qrow * HDIM + ks * 16 + hi * 8);

    f32x16 oacc[2];
#pragma unroll
    for (int df = 0; df < 2; ++df)
#pragma unroll
      for (int r = 0; r < 16; ++r) oacc[df][r] = 0.f;
    float m_run = -3.0e38f, l_run = 0.f;

    bf16x8 kreg[2], vreg[2];
#pragma unroll
    for (int j = 0; j < 2; ++j) {
      const int rr = j * 32 + srow;
      kreg[j] = *(const bf16x8*)(Kh + (size_t)rr * HDIM + scol);
      vreg[j] = *(const bf16x8*)(Vh + (size_t)rr * SEQ + scol);
    }
    __syncthreads();
#pragma unroll
    for (int j = 0; j < 2; ++j) {
      const int rr = j * 32 + srow;
      *(bf16x8*)(K_lds[0] + rr * 72 + scol) = kreg[j];
      *(bf16x8*)(V_lds[0] + rr * 72 + scol) = vreg[j];
    }

    for (int t = 0; t < n_tiles; ++t) {
      const int cur = t & 1;
      const bool not_last = (t + 1 < n_tiles);
      if (not_last) {
#pragma unroll
        for (int j = 0; j < 2; ++j) {
          const int rr = j * 32 + srow;
          kreg[j] = *(const bf16x8*)(Kh + (size_t)((t + 1) * 64 + rr) * HDIM + scol);
          vreg[j] = *(const bf16x8*)(Vh + (size_t)rr * SEQ + (t + 1) * 64 + scol);
        }
      }
      __syncthreads();

      if (t * 64 <= wrow_max) {
        f32x16 skf[2];
#pragma unroll
        for (int kf = 0; kf < 2; ++kf)
#pragma unroll
          for (int r = 0; r < 16; ++r) skf[kf][r] = 0.f;
        __builtin_amdgcn_s_setprio(1);
#pragma unroll
        for (int kf = 0; kf < 2; ++kf)
#pragma unroll
          for (int ks = 0; ks < 4; ++ks) {
            bf16x8 ak = *(const bf16x8*)(K_lds[cur] + (kf * 32 + q5) * 72 + ks * 16 + hi * 8);
            skf[kf] = __builtin_amdgcn_mfma_f32_32x32x16_bf16(ak, qf[ks], skf[kf], 0, 0, 0);
          }
        __builtin_amdgcn_s_setprio(0);

        const bool need_mask = (t * 64 + 63 > wrow0);
        if (need_mask) {
#pragma unroll
          for (int kf = 0; kf < 2; ++kf)
#pragma unroll
            for (int r = 0; r < 16; ++r) {
              const int key = t * 64 + kf * 32 + (r & 3) + 8 * (r >> 2) + 4 * hi;
              if (key > qrow) skf[kf][r] = -3.0e38f;
            }
        }

        float mx = -3.0e38f;
#pragma unroll
        for (int kf = 0; kf < 2; ++kf)
#pragma unroll
          for (int r = 0; r < 16; ++r) mx = fmaxf(mx, skf[kf][r]);
        mx = fmaxf(mx, __shfl_xor(mx, 32));

        if (__any(mx > m_run + 8.0f)) {
          const float mnew = fmaxf(m_run, mx);
          const float alpha = exp2f(m_run - mnew);
          m_run = mnew;
          l_run *= alpha;
          if (l < 32) abuf[w][l] = alpha;
          f32x4 av[4];
#pragma unroll
          for (int k = 0; k < 4; ++k)
            av[k] = *(const f32x4*)&abuf[w][8 * k + 4 * hi];
#pragma unroll
          for (int df = 0; df < 2; ++df)
#pragma unroll
            for (int r = 0; r < 16; ++r) oacc[df][r] *= av[r >> 2][r & 3];
        }

        unsigned int pkA[8], pkB[8];
        float psum = 0.f;
#pragma unroll
        for (int kf = 0; kf < 2; ++kf)
#pragma unroll
          for (int rr = 0; rr < 4; ++rr) {
            unsigned int pb[4];
#pragma unroll
            for (int j = 0; j < 4; ++j) {
              const float p = exp2f(skf[kf][rr * 4 + j] - m_run);
              psum += p;
              union { float f; unsigned int u; } c; c.f = p;
              pb[j] = c.u + 0x8000u;
            }
            pkA[kf * 4 + rr] = __builtin_amdgcn_perm(pb[1], pb[0], 0x07060302);
            pkB[kf * 4 + rr] = __builtin_amdgcn_perm(pb[3], pb[2], 0x07060302);
          }
        psum += __shfl_xor(psum, 32);
        l_run += psum;

        __builtin_amdgcn_s_setprio(1);
#pragma unroll
        for (int ks = 0; ks < 4; ++ks) {
          u32x2 ra = __builtin_amdgcn_permlane32_swap(pkA[2 * ks], pkA[2 * ks + 1], false, false);
          u32x2 rb = __builtin_amdgcn_permlane32_swap(pkB[2 * ks], pkB[2 * ks + 1], false, false);
          union { unsigned int u[4]; bf16x8 v; } pa;
          pa.u[0] = ra.x; pa.u[1] = rb.x; pa.u[2] = ra.y; pa.u[3] = rb.y;
#pragma unroll
          for (int df = 0; df < 2; ++df) {
            bf16x8 vf = *(const bf16x8*)(V_lds[cur] + (df * 32 + q5) * 72 + ks * 16 + hi * 8);
            oacc[df] = __builtin_amdgcn_mfma_f32_32x32x16_bf16(pa.v, vf, oacc[df], 0, 0, 0);
          }
        }
        __builtin_amdgcn_s_setprio(0);
      }

      if (not_last) {
#pragma unroll
        for (int j = 0; j < 2; ++j) {
          const int rr = j * 32 + srow;
          *(bf16x8*)(K_lds[cur ^ 1] + rr * 72 + scol) = kreg[j];
          *(bf16x8*)(V_lds[cur ^ 1] + rr * 72 + scol) = vreg[j];
        }
      }
    }

    if (l < 32) lbuf[w][l] = l_run;
    f32x4 lv[4];
#pragma unroll
    for (int k = 0; k < 4; ++k)
      lv[k] = *(const f32x4*)&lbuf[w][8 * k + 4 * hi];
#pragma unroll
    for (int df = 0; df < 2; ++df) {
      const int d = df * 32 + q5;
#pragma unroll
      for (int r = 0; r < 16; ++r) {
        const int s = wrow0 + (r & 3) + 8 * (r >> 2) + 4 * hi;
        const float inv = __builtin_amdgcn_rcpf(lv[r >> 2][r & 3]);
        O[((size_t)(bq * SEQ + s)) * EMBED + hh * HDIM + d] = f2bf(oacc[df][r] * inv);
      }
    }
  }
}

extern "C" void kernel_launch(void* const* d_in, const int* in_sizes, int n_in,
                              void* d_out, int out_size, void* d_ws, size_t ws_size,
                              hipStream_t stream) {
  const float* h  = (const float*)d_in[0];
  const float* Wq = (const float*)d_in[1];
  const float* bq = (const float*)d_in[2];
  const float* Wk = (const float*)d_in[3];
  const float* bk = (const float*)d_in[4];
  const float* Wv = (const float*)d_in[5];
  const float* bv = (const float*)d_in[6];
  const float* Wo = (const float*)d_in[7];
  const float* bo = (const float*)d_in[8];

  if (ws_size < (size_t)117440512) return;

  unsigned short* ws = (unsigned short*)d_ws;
  unsigned short* hb = ws;                    // [4096,2048] bf16
  unsigned short* wqb = ws + 8388608;         // [6144,2048] contiguous QKV weights
  unsigned short* wob = ws + 20971520;
  unsigned short* Qw  = ws + 25165824;        // [B,H,S,D] (pre-scaled)
  unsigned short* Kw  = ws + 33554432;        // [B,H,S,D]
  unsigned short* Vw  = ws + 41943040;        // [B,H,D,S]
  unsigned short* Ow  = ws + 50331648;        // [B,S,E]

  cvt_all<<<2048, 256, 0, stream>>>(h, Wq, Wk, Wv, Wo, ws);

  const float qscale = ATT_SCALE * LOG2E;
  gemm256_qkv<<<384, 512, 0, stream>>>(hb, wqb, bq, bk, bv, Qw, Kw, Vw, qscale);

  attn_kernel<<<512, 256, 0, stream>>>(Qw, Kw, Vw, Ow);

  gemm8_out<<<256, 512, 0, stream>>>(Ow, wob, bo, (float*)d_out);
}

// Round 8
// 249.440 us; speedup vs baseline: 1.1071x; 1.1071x over previous
//
#include <hip/hip_runtime.h>
#include <hip/hip_bf16.h>
#include <stdint.h>

#define EMBED 2048
#define NHEADS 32
#define HDIM 64
#define BATCH 2
#define SEQ 2048
#define ATT_SCALE 0.125f
#define LOG2E 1.4426950408889634f

typedef __attribute__((ext_vector_type(8))) short bf16x8;
typedef __attribute__((ext_vector_type(4))) float f32x4;
typedef __attribute__((ext_vector_type(16))) float f32x16;
typedef __attribute__((ext_vector_type(4))) unsigned short u16x4;
typedef __attribute__((ext_vector_type(2))) unsigned int u32x2;

static __device__ __forceinline__ unsigned short f2bf(float f) {
  union { float f; uint32_t u; } v; v.f = f;
  uint32_t r = v.u + 0x7fffu + ((v.u >> 16) & 1u);
  return (unsigned short)(r >> 16);
}

static __device__ __forceinline__ void gload_lds16(const unsigned short* g, unsigned short* l) {
  __builtin_amdgcn_global_load_lds(
      (const __attribute__((address_space(1))) unsigned int*)g,
      (__attribute__((address_space(3))) unsigned int*)l, 16, 0, 0);
}

// ---------------- fp32 -> bf16 cast, all 5 tensors fused ----------------
__global__ void cvt_all(const float* __restrict__ h,
                        const float* __restrict__ Wq, const float* __restrict__ Wk,
                        const float* __restrict__ Wv, const float* __restrict__ Wo,
                        unsigned short* __restrict__ out) {
  const int n4 = 6291456;
  int idx = blockIdx.x * blockDim.x + threadIdx.x;
  int stride = gridDim.x * blockDim.x;
  for (int i = idx; i < n4; i += stride) {
    const float* src; int off;
    if (i < 2097152)      { src = h;  off = i; }
    else if (i < 3145728) { src = Wq; off = i - 2097152; }
    else if (i < 4194304) { src = Wk; off = i - 3145728; }
    else if (i < 5242880) { src = Wv; off = i - 4194304; }
    else                  { src = Wo; off = i - 5242880; }
    float4 v = ((const float4*)src)[off];
    u16x4 o;
    o.x = f2bf(v.x); o.y = f2bf(v.y); o.z = f2bf(v.z); o.w = f2bf(v.w);
    ((u16x4*)out)[i] = o;
  }
}

// ---------------- 256x192 2-phase pipelined GEMM for QKV ----------------
// C[4096,6144] = A[4096,2048] @ W[6144,2048]^T, fused QKV epilogue.
// BM=256, BN=192, BK=64; 512 threads = 8 waves (2M x 4N), wave tile 128x48.
// Grid 16x32 = 512 blocks = exactly 2 full rounds at 1 blk/CU.
// 2 phases/K-tile, 24 MFMA each; counted vmcnt(3)/vmcnt(2), never 0 steady-state.
// LDS swizzle: LDS[r][u] = G[r][u ^ (r&7)] (16B units), both sides.
__global__ __launch_bounds__(512, 2)
void gemm_qkv192(const unsigned short* __restrict__ A,
                 const unsigned short* __restrict__ W,
                 const float* __restrict__ b0, const float* __restrict__ b1,
                 const float* __restrict__ b2,
                 unsigned short* __restrict__ o0, unsigned short* __restrict__ o1,
                 unsigned short* __restrict__ o2, float qscale) {
  __shared__ unsigned short lds[2][28672];  // per buf: A [256][64] @0, B [192][64] @16384
  const int tid = threadIdx.x;
  const int w = tid >> 6, l = tid & 63;
  const int wm = w >> 2, wn = w & 3;
  const int r16 = l & 15, g = l >> 4;
  // XCD 2x4 chunk map over 16 bi x 32 bj: xcd (xr,xc) owns bi in [xr*8,+8), bj in [xc*8,+8)
  const int xcd = blockIdx.x & 7, t8 = blockIdx.x >> 3;   // t8 in [0,64)
  const int bi = (xcd >> 2) * 8 + (t8 & 7);
  const int bj = (xcd & 3) * 8 + (t8 >> 3);
  const int arow0 = bi * 256, bcol0 = bj * 192;

  f32x4 acc[8][3];
#pragma unroll
  for (int i = 0; i < 8; ++i)
#pragma unroll
    for (int j = 0; j < 3; ++j) acc[i][j] = (f32x4){0.f, 0.f, 0.f, 0.f};

  const int lr8 = (l >> 3) & 7;
  const int gcu = ((l & 7) ^ lr8) * 8;   // pre-swizzled source col (elements)

  // A call: 64 rows starting at `base` (base in {0,64,128,192})
  auto stageA = [&](int buf, int kt, int base) {
    gload_lds16(A + (size_t)(arow0 + base + (tid >> 3)) * 2048 + kt * 64 + gcu,
                &lds[buf][(base + w * 8) * 64]);
  };
  // B call: 64 rows starting at k*64, k in {0,1,2}
  auto stageB = [&](int buf, int kt, int k) {
    gload_lds16(W + (size_t)(bcol0 + k * 64 + (tid >> 3)) * 2048 + kt * 64 + gcu,
                &lds[buf][16384 + (k * 64 + w * 8) * 64]);
  };
  auto ldA = [&](int buf, int mf, int ks) -> bf16x8 {
    const int row = wm * 128 + mf * 16 + r16;
    const int u = (ks * 4 + g) ^ (r16 & 7);
    return *(const bf16x8*)&lds[buf][row * 64 + u * 8];
  };
  auto ldB = [&](int buf, int nf, int ks) -> bf16x8 {
    const int row = wn * 48 + nf * 16 + r16;
    const int u = (ks * 4 + g) ^ (r16 & 7);
    return *(const bf16x8*)&lds[buf][16384 + row * 64 + u * 8];
  };

  bf16x8 af[4][2], bfr[3][2];

#define MMA_H(MH)                                                                  \
  __builtin_amdgcn_s_setprio(1);                                                   \
  _Pragma("unroll")                                                                \
  for (int i = 0; i < 4; ++i)                                                      \
    _Pragma("unroll")                                                              \
    for (int j = 0; j < 3; ++j)                                                    \
      _Pragma("unroll")                                                            \
      for (int ks = 0; ks < 2; ++ks)                                               \
        acc[(MH)*4 + i][j] = __builtin_amdgcn_mfma_f32_16x16x32_bf16(              \
            af[i][ks], bfr[j][ks], acc[(MH)*4 + i][j], 0, 0, 0);                   \
  __builtin_amdgcn_s_setprio(0);

  // prologue: tile 0 -> buf0; A-late (64,192) issued LAST (stay in flight)
  stageB(0, 0, 0); stageB(0, 0, 1); stageB(0, 0, 2);
  stageA(0, 0, 0); stageA(0, 0, 128);
  stageA(0, 0, 64); stageA(0, 0, 192);
  asm volatile("s_waitcnt vmcnt(2)" ::: "memory");
  __builtin_amdgcn_sched_barrier(0);
  __builtin_amdgcn_s_barrier();

  const int nt = 32;  // K = 2048 / 64
  for (int c = 0; c < nt; ++c) {
    const int X = c & 1, Y = X ^ 1;
    const bool s1 = (c + 1 < nt);
    // ---- Phase 0: mh0 (A rows wm*128+0..63 = bases {0,128}); stage B(c+1)
#pragma unroll
    for (int i = 0; i < 4; ++i) { af[i][0] = ldA(X, i, 0); af[i][1] = ldA(X, i, 1); }
#pragma unroll
    for (int j = 0; j < 3; ++j) { bfr[j][0] = ldB(X, j, 0); bfr[j][1] = ldB(X, j, 1); }
    if (s1) { stageB(Y, c + 1, 0); stageB(Y, c + 1, 1); stageB(Y, c + 1, 2); }
    MMA_H(0);
    __builtin_amdgcn_s_barrier();
    // ---- Phase 1: mh1 (bases {64,192} = A-late(c)): gate vmcnt; stage A(c+1)
    if (s1) asm volatile("s_waitcnt vmcnt(3)" ::: "memory");
    else    asm volatile("s_waitcnt vmcnt(0)" ::: "memory");
    __builtin_amdgcn_sched_barrier(0);
#pragma unroll
    for (int i = 0; i < 4; ++i) { af[i][0] = ldA(X, i + 4, 0); af[i][1] = ldA(X, i + 4, 1); }
    if (s1) {
      stageA(Y, c + 1, 0); stageA(Y, c + 1, 128);   // early
      stageA(Y, c + 1, 64); stageA(Y, c + 1, 192);  // late (left in flight)
    }
    MMA_H(1);
    if (s1) asm volatile("s_waitcnt vmcnt(2)" ::: "memory");
    else    asm volatile("s_waitcnt vmcnt(0)" ::: "memory");
    __builtin_amdgcn_sched_barrier(0);
    __builtin_amdgcn_s_barrier();
  }
#undef MMA_H

  // epilogue: bias + scale + QKV scatter (which resolved per fragment-column;
  // 16-col fragments never straddle the 2048 boundaries)
#pragma unroll
  for (int mf = 0; mf < 8; ++mf) {
    const int irow = arow0 + wm * 128 + mf * 16 + g * 4;
#pragma unroll
    for (int nf = 0; nf < 3; ++nf) {
      const int jcol = bcol0 + wn * 48 + nf * 16 + r16;
      const int which = jcol >> 11;  // 0=Q 1=K 2=V
      const int jl = jcol & 2047;
      const int hh = jl >> 6, d = jl & 63;
      const float bval = (which == 0) ? b0[jl] : (which == 1) ? b1[jl] : b2[jl];
      const float osc = (which == 0) ? qscale : 1.0f;
      unsigned short* outp = (which == 0) ? o0 : (which == 1) ? o1 : o2;
#pragma unroll
      for (int rr = 0; rr < 4; ++rr) {
        const float val = (acc[mf][nf][rr] + bval) * osc;
        const int i = irow + rr;
        const int b = i >> 11, s = i & 2047;
        size_t off;
        if (which < 2) off = (((size_t)(b * NHEADS + hh)) * SEQ + s) * HDIM + d;
        else           off = (((size_t)(b * NHEADS + hh)) * HDIM + d) * SEQ + s;
        outp[off] = f2bf(val);
      }
    }
  }
}

// ---------------- 256x128 pipelined GEMM (out-proj): fp32 out + bias ----------------
__global__ __launch_bounds__(512, 2)
void gemm8_out(const unsigned short* __restrict__ A,
               const unsigned short* __restrict__ W,
               const float* __restrict__ bias, float* __restrict__ fo) {
  __shared__ unsigned short lds[2][24576];   // per buf: A [256][64] @0, B [128][64] @16384
  const int tid = threadIdx.x;
  const int w = tid >> 6, l = tid & 63;
  const int wm = w >> 1, wn = w & 1;
  const int r16 = l & 15, g = l >> 4;
  const int NBJ = 16, nblk = 256;
  const int swz = (blockIdx.x & 7) * (nblk >> 3) + (blockIdx.x >> 3);
  const int bi = swz / NBJ, bj = swz % NBJ;
  const int arow0 = bi * 256, bcol0 = bj * 128;

  f32x4 acc[4][4];
#pragma unroll
  for (int i = 0; i < 4; ++i)
#pragma unroll
    for (int j = 0; j < 4; ++j) acc[i][j] = (f32x4){0.f, 0.f, 0.f, 0.f};

  const int lrow = l >> 3;
  const int gcu = ((l & 7) ^ lrow) * 8;

  auto stageA = [&](int buf, int t, int mq, int call) {
    const int m = call * 8 + w;
    const int row0 = mq * 32 + (m >> 2) * 64 + (m & 3) * 8;
    gload_lds16(A + (size_t)(arow0 + row0 + lrow) * 2048 + t * 64 + gcu,
                &lds[buf][row0 * 64]);
  };
  auto stageB = [&](int buf, int t, int nq) {
    const int row0 = nq * 32 + (w >> 2) * 64 + (w & 3) * 8;
    gload_lds16(W + (size_t)(bcol0 + row0 + lrow) * 2048 + t * 64 + gcu,
                &lds[buf][16384 + row0 * 64]);
  };
  auto ldA = [&](int buf, int mf, int ks) -> bf16x8 {
    const int row = wm * 64 + mf * 16 + r16;
    const int u = (ks * 4 + g) ^ (r16 & 7);
    return *(const bf16x8*)&lds[buf][row * 64 + u * 8];
  };
  auto ldB = [&](int buf, int nf, int ks) -> bf16x8 {
    const int row = wn * 64 + nf * 16 + r16;
    const int u = (ks * 4 + g) ^ (r16 & 7);
    return *(const bf16x8*)&lds[buf][16384 + row * 64 + u * 8];
  };

  stageA(0, 0, 0, 0); stageA(0, 0, 0, 1); stageB(0, 0, 0);
  stageA(0, 0, 1, 0); stageA(0, 0, 1, 1); stageB(0, 0, 1);
  stageA(1, 1, 0, 0); stageA(1, 1, 0, 1); stageB(1, 1, 0);
  asm volatile("s_waitcnt vmcnt(3)" ::: "memory");
  __builtin_amdgcn_sched_barrier(0);
  __builtin_amdgcn_s_barrier();

  bf16x8 af[2][2], bfr[4][2];

#define MMA_Q(MQ, NQ)                                                          \
  __builtin_amdgcn_s_setprio(1);                                               \
  _Pragma("unroll")                                                            \
  for (int i = 0; i < 2; ++i)                                                  \
    _Pragma("unroll")                                                          \
    for (int j = 0; j < 2; ++j)                                                \
      _Pragma("unroll")                                                        \
      for (int ks = 0; ks < 2; ++ks)                                           \
        acc[(MQ)*2 + i][(NQ)*2 + j] = __builtin_amdgcn_mfma_f32_16x16x32_bf16( \
            af[i][ks], bfr[(NQ)*2 + j][ks], acc[(MQ)*2 + i][(NQ)*2 + j], 0, 0, 0); \
  __builtin_amdgcn_s_setprio(0);

  const int nt = 32;
  for (int c = 0; c < nt; ++c) {
    const int X = c & 1;
    const bool s1 = (c + 1 < nt), s2 = (c + 2 < nt);
    af[0][0] = ldA(X, 0, 0); af[0][1] = ldA(X, 0, 1);
    af[1][0] = ldA(X, 1, 0); af[1][1] = ldA(X, 1, 1);
    bfr[0][0] = ldB(X, 0, 0); bfr[0][1] = ldB(X, 0, 1);
    bfr[1][0] = ldB(X, 1, 0); bfr[1][1] = ldB(X, 1, 1);
    if (s1) { stageA(X ^ 1, c + 1, 1, 0); stageA(X ^ 1, c + 1, 1, 1); }
    MMA_Q(0, 0);
    __builtin_amdgcn_s_barrier();
    bfr[2][0] = ldB(X, 2, 0); bfr[2][1] = ldB(X, 2, 1);
    bfr[3][0] = ldB(X, 3, 0); bfr[3][1] = ldB(X, 3, 1);
    if (s1) stageB(X ^ 1, c + 1, 1);
    MMA_Q(0, 1);
    __builtin_amdgcn_s_barrier();
    af[0][0] = ldA(X, 2, 0); af[0][1] = ldA(X, 2, 1);
    af[1][0] = ldA(X, 3, 0); af[1][1] = ldA(X, 3, 1);
    if (s2) { stageA(X, c + 2, 0, 0); stageA(X, c + 2, 0, 1); }
    MMA_Q(1, 0);
    __builtin_amdgcn_s_barrier();
    if (s2) stageB(X, c + 2, 0);
    MMA_Q(1, 1);
    if (s2) asm volatile("s_waitcnt vmcnt(3)" ::: "memory");
    else    asm volatile("s_waitcnt vmcnt(0)" ::: "memory");
    __builtin_amdgcn_sched_barrier(0);
    __builtin_amdgcn_s_barrier();
  }
#undef MMA_Q

#pragma unroll
  for (int mf = 0; mf < 4; ++mf) {
    const int irow = arow0 + wm * 64 + mf * 16 + g * 4;
#pragma unroll
    for (int nf = 0; nf < 4; ++nf) {
      const int jcol = bcol0 + wn * 64 + nf * 16 + r16;
      const float bval = bias[jcol];
#pragma unroll
      for (int rr = 0; rr < 4; ++rr)
        fo[(size_t)(irow + rr) * 2048 + jcol] = acc[mf][nf][rr] + bval;
    }
  }
}

// ---------------- causal flash attention, swapped 32x32 QK^T, in-register softmax ----------------
__global__ __launch_bounds__(256, 2)
void attn_kernel(const unsigned short* __restrict__ Q,
                 const unsigned short* __restrict__ K,
                 const unsigned short* __restrict__ Vt,
                 unsigned short* __restrict__ O) {
  __shared__ unsigned short K_lds[2][64 * 72];
  __shared__ unsigned short V_lds[2][64 * 72];
  __shared__ __align__(16) float abuf[4][32];
  __shared__ __align__(16) float lbuf[4][32];
  const int tid = threadIdx.x;
  const int w = tid >> 6, l = tid & 63;
  const int q5 = l & 31, hi = l >> 5;
  const int bid = ((blockIdx.x & 7) << 6) | (blockIdx.x >> 3);
  const int pair = bid & 7;
  const int bh = bid >> 3;
  const unsigned short* Qh = Q + (size_t)bh * SEQ * HDIM;
  const unsigned short* Kh = K + (size_t)bh * SEQ * HDIM;
  const unsigned short* Vh = Vt + (size_t)bh * HDIM * SEQ;
  const int bq = bh >> 5, hh = bh & 31;
  const int srow = tid >> 3;
  const int scol = (tid & 7) * 8;

  for (int half = 0; half < 2; ++half) {
    const int qt = half ? (15 - pair) : pair;
    const int wrow0 = qt * 128 + w * 32;
    const int wrow_max = wrow0 + 31;
    const int n_tiles = 2 * qt + 2;
    const int qrow = wrow0 + q5;

    bf16x8 qf[4];
#pragma unroll
    for (int ks = 0; ks < 4; ++ks)
      qf[ks] = *(const bf16x8*)(Qh + (size_t)qrow * HDIM + ks * 16 + hi * 8);

    f32x16 oacc[2];
#pragma unroll
    for (int df = 0; df < 2; ++df)
#pragma unroll
      for (int r = 0; r < 16; ++r) oacc[df][r] = 0.f;
    float m_run = -3.0e38f, l_run = 0.f;

    bf16x8 kreg[2], vreg[2];
#pragma unroll
    for (int j = 0; j < 2; ++j) {
      const int rr = j * 32 + srow;
      kreg[j] = *(const bf16x8*)(Kh + (size_t)rr * HDIM + scol);
      vreg[j] = *(const bf16x8*)(Vh + (size_t)rr * SEQ + scol);
    }
    __syncthreads();
#pragma unroll
    for (int j = 0; j < 2; ++j) {
      const int rr = j * 32 + srow;
      *(bf16x8*)(K_lds[0] + rr * 72 + scol) = kreg[j];
      *(bf16x8*)(V_lds[0] + rr * 72 + scol) = vreg[j];
    }

    for (int t = 0; t < n_tiles; ++t) {
      const int cur = t & 1;
      const bool not_last = (t + 1 < n_tiles);
      if (not_last) {
#pragma unroll
        for (int j = 0; j < 2; ++j) {
          const int rr = j * 32 + srow;
          kreg[j] = *(const bf16x8*)(Kh + (size_t)((t + 1) * 64 + rr) * HDIM + scol);
          vreg[j] = *(const bf16x8*)(Vh + (size_t)rr * SEQ + (t + 1) * 64 + scol);
        }
      }
      __syncthreads();

      if (t * 64 <= wrow_max) {
        f32x16 skf[2];
#pragma unroll
        for (int kf = 0; kf < 2; ++kf)
#pragma unroll
          for (int r = 0; r < 16; ++r) skf[kf][r] = 0.f;
        __builtin_amdgcn_s_setprio(1);
#pragma unroll
        for (int kf = 0; kf < 2; ++kf)
#pragma unroll
          for (int ks = 0; ks < 4; ++ks) {
            bf16x8 ak = *(const bf16x8*)(K_lds[cur] + (kf * 32 + q5) * 72 + ks * 16 + hi * 8);
            skf[kf] = __builtin_amdgcn_mfma_f32_32x32x16_bf16(ak, qf[ks], skf[kf], 0, 0, 0);
          }
        __builtin_amdgcn_s_setprio(0);

        const bool need_mask = (t * 64 + 63 > wrow0);
        if (need_mask) {
#pragma unroll
          for (int kf = 0; kf < 2; ++kf)
#pragma unroll
            for (int r = 0; r < 16; ++r) {
              const int key = t * 64 + kf * 32 + (r & 3) + 8 * (r >> 2) + 4 * hi;
              if (key > qrow) skf[kf][r] = -3.0e38f;
            }
        }

        float mx = -3.0e38f;
#pragma unroll
        for (int kf = 0; kf < 2; ++kf)
#pragma unroll
          for (int r = 0; r < 16; ++r) mx = fmaxf(mx, skf[kf][r]);
        mx = fmaxf(mx, __shfl_xor(mx, 32));

        if (__any(mx > m_run + 8.0f)) {
          const float mnew = fmaxf(m_run, mx);
          const float alpha = exp2f(m_run - mnew);
          m_run = mnew;
          l_run *= alpha;
          if (l < 32) abuf[w][l] = alpha;
          f32x4 av[4];
#pragma unroll
          for (int k = 0; k < 4; ++k)
            av[k] = *(const f32x4*)&abuf[w][8 * k + 4 * hi];
#pragma unroll
          for (int df = 0; df < 2; ++df)
#pragma unroll
            for (int r = 0; r < 16; ++r) oacc[df][r] *= av[r >> 2][r & 3];
        }

        unsigned int pkA[8], pkB[8];
        float psum = 0.f;
#pragma unroll
        for (int kf = 0; kf < 2; ++kf)
#pragma unroll
          for (int rr = 0; rr < 4; ++rr) {
            unsigned int pb[4];
#pragma unroll
            for (int j = 0; j < 4; ++j) {
              const float p = exp2f(skf[kf][rr * 4 + j] - m_run);
              psum += p;
              union { float f; unsigned int u; } c; c.f = p;
              pb[j] = c.u + 0x8000u;
            }
            pkA[kf * 4 + rr] = __builtin_amdgcn_perm(pb[1], pb[0], 0x07060302);
            pkB[kf * 4 + rr] = __builtin_amdgcn_perm(pb[3], pb[2], 0x07060302);
          }
        psum += __shfl_xor(psum, 32);
        l_run += psum;

        __builtin_amdgcn_s_setprio(1);
#pragma unroll
        for (int ks = 0; ks < 4; ++ks) {
          u32x2 ra = __builtin_amdgcn_permlane32_swap(pkA[2 * ks], pkA[2 * ks + 1], false, false);
          u32x2 rb = __builtin_amdgcn_permlane32_swap(pkB[2 * ks], pkB[2 * ks + 1], false, false);
          union { unsigned int u[4]; bf16x8 v; } pa;
          pa.u[0] = ra.x; pa.u[1] = rb.x; pa.u[2] = ra.y; pa.u[3] = rb.y;
#pragma unroll
          for (int df = 0; df < 2; ++df) {
            bf16x8 vf = *(const bf16x8*)(V_lds[cur] + (df * 32 + q5) * 72 + ks * 16 + hi * 8);
            oacc[df] = __builtin_amdgcn_mfma_f32_32x32x16_bf16(pa.v, vf, oacc[df], 0, 0, 0);
          }
        }
        __builtin_amdgcn_s_setprio(0);
      }

      if (not_last) {
#pragma unroll
        for (int j = 0; j < 2; ++j) {
          const int rr = j * 32 + srow;
          *(bf16x8*)(K_lds[cur ^ 1] + rr * 72 + scol) = kreg[j];
          *(bf16x8*)(V_lds[cur ^ 1] + rr * 72 + scol) = vreg[j];
        }
      }
    }

    if (l < 32) lbuf[w][l] = l_run;
    f32x4 lv[4];
#pragma unroll
    for (int k = 0; k < 4; ++k)
      lv[k] = *(const f32x4*)&lbuf[w][8 * k + 4 * hi];
#pragma unroll
    for (int df = 0; df < 2; ++df) {
      const int d = df * 32 + q5;
#pragma unroll
      for (int r = 0; r < 16; ++r) {
        const int s = wrow0 + (r & 3) + 8 * (r >> 2) + 4 * hi;
        const float inv = __builtin_amdgcn_rcpf(lv[r >> 2][r & 3]);
        O[((size_t)(bq * SEQ + s)) * EMBED + hh * HDIM + d] = f2bf(oacc[df][r] * inv);
      }
    }
  }
}

extern "C" void kernel_launch(void* const* d_in, const int* in_sizes, int n_in,
                              void* d_out, int out_size, void* d_ws, size_t ws_size,
                              hipStream_t stream) {
  const float* h  = (const float*)d_in[0];
  const float* Wq = (const float*)d_in[1];
  const float* bq = (const float*)d_in[2];
  const float* Wk = (const float*)d_in[3];
  const float* bk = (const float*)d_in[4];
  const float* Wv = (const float*)d_in[5];
  const float* bv = (const float*)d_in[6];
  const float* Wo = (const float*)d_in[7];
  const float* bo = (const float*)d_in[8];

  if (ws_size < (size_t)117440512) return;

  unsigned short* ws = (unsigned short*)d_ws;
  unsigned short* hb = ws;                    // [4096,2048] bf16
  unsigned short* wqb = ws + 8388608;         // [6144,2048] contiguous QKV weights
  unsigned short* wob = ws + 20971520;
  unsigned short* Qw  = ws + 25165824;        // [B,H,S,D] (pre-scaled)
  unsigned short* Kw  = ws + 33554432;        // [B,H,S,D]
  unsigned short* Vw  = ws + 41943040;        // [B,H,D,S]
  unsigned short* Ow  = ws + 50331648;        // [B,S,E]

  cvt_all<<<2048, 256, 0, stream>>>(h, Wq, Wk, Wv, Wo, ws);

  const float qscale = ATT_SCALE * LOG2E;
  gemm_qkv192<<<512, 512, 0, stream>>>(hb, wqb, bq, bk, bv, Qw, Kw, Vw, qscale);

  attn_kernel<<<512, 256, 0, stream>>>(Qw, Kw, Vw, Ow);

  gemm8_out<<<256, 512, 0, stream>>>(Ow, wob, bo, (float*)d_out);
}